// Round 2
// baseline (1206.674 us; speedup 1.0000x reference)
//
#include <hip/hip_runtime.h>
#include <hip/hip_bf16.h>
#include <math.h>

typedef short s16x8 __attribute__((ext_vector_type(8)));
typedef float f32x4 __attribute__((ext_vector_type(4)));
typedef unsigned short u16;

#define NB_ 8

__device__ __forceinline__ float bf2f(__hip_bfloat16 v){ return __bfloat162float(v); }
__device__ __forceinline__ __hip_bfloat16 f2bf(float v){ return __float2bfloat16(v); }

// ---------------------------------------------------------------------------
// GEMM: C[M,N] = A[M,K] @ B[K,N], A bf16 [M,K], B given transposed bf16 BT[N,K].
// A may be split at column `ksplit` between two sources (for concat([c,b])).
// MODE 0: +bias, exact gelu, bf16 out
// MODE 1: +bias, tanh, bf16 out
// MODE 2: +bias, torsion gate + signal + residual, fp32 x in-place
// MODE 3: +bias, fp32 out
// ---------------------------------------------------------------------------
template<int MODE>
__global__ __launch_bounds__(256)
void gemm_mfma(const __hip_bfloat16* __restrict__ A0, int lda0,
               const __hip_bfloat16* __restrict__ A1, int lda1, int ksplit,
               const __hip_bfloat16* __restrict__ BT,
               const float* __restrict__ bias_base, int bias_stride,
               const int* __restrict__ idx_ptr,
               int M, int N, int K,
               __hip_bfloat16* __restrict__ outb,
               float* __restrict__ xio,
               const float* __restrict__ gate_base, int gate_stride,
               const float* __restrict__ torsion,
               const float* __restrict__ meansig)
{
    __shared__ u16 As[128 * 72];
    __shared__ u16 Bs[128 * 72];
    const int tid  = threadIdx.x;
    const int m0   = blockIdx.x * 128;
    const int n0   = blockIdx.y * 128;
    const int wave = tid >> 6, lane = tid & 63;
    const int wm   = (wave >> 1) * 64, wn = (wave & 1) * 64;
    const int lrow = lane & 15, quad = lane >> 4;

    f32x4 acc[4][4];
#pragma unroll
    for (int i = 0; i < 4; i++)
#pragma unroll
        for (int j = 0; j < 4; j++) {
            f32x4 z = {0.f, 0.f, 0.f, 0.f};
            acc[i][j] = z;
        }

    for (int k0 = 0; k0 < K; k0 += 64) {
        const u16* Ab; int ldA; int kk;
        if (k0 < ksplit) { Ab = (const u16*)A0; ldA = lda0; kk = k0; }
        else             { Ab = (const u16*)A1; ldA = lda1; kk = k0 - ksplit; }
#pragma unroll
        for (int i = 0; i < 4; i++) {
            int q = tid + i * 256;
            int row = q >> 3, c8 = (q & 7) << 3;
            uint4 v = *(const uint4*)(Ab + (size_t)(m0 + row) * ldA + kk + c8);
            *(uint4*)&As[row * 72 + c8] = v;
        }
#pragma unroll
        for (int i = 0; i < 4; i++) {
            int q = tid + i * 256;
            int row = q >> 3, c8 = (q & 7) << 3;
            uint4 v = *(const uint4*)((const u16*)BT + (size_t)(n0 + row) * K + k0 + c8);
            *(uint4*)&Bs[row * 72 + c8] = v;
        }
        __syncthreads();
#pragma unroll
        for (int ks = 0; ks < 64; ks += 32) {
            s16x8 af[4], bfr[4];
#pragma unroll
            for (int i = 0; i < 4; i++)
                af[i] = *(const s16x8*)&As[(wm + i * 16 + lrow) * 72 + ks + quad * 8];
#pragma unroll
            for (int j = 0; j < 4; j++)
                bfr[j] = *(const s16x8*)&Bs[(wn + j * 16 + lrow) * 72 + ks + quad * 8];
#pragma unroll
            for (int i = 0; i < 4; i++)
#pragma unroll
                for (int j = 0; j < 4; j++)
                    acc[i][j] = __builtin_amdgcn_mfma_f32_16x16x32_bf16(af[i], bfr[j], acc[i][j], 0, 0, 0);
        }
        __syncthreads();
    }

    const int idx = idx_ptr ? idx_ptr[0] : 0;
    const float* bias = bias_base + (size_t)idx * bias_stride;
    const float* gate = (MODE == 2) ? (gate_base + (size_t)idx * gate_stride) : nullptr;

#pragma unroll
    for (int i = 0; i < 4; i++) {
#pragma unroll
        for (int r = 0; r < 4; r++) {
            int m = m0 + wm + i * 16 + quad * 4 + r;
#pragma unroll
            for (int j = 0; j < 4; j++) {
                int n = n0 + wn + j * 16 + lrow;
                float v = acc[i][j][r] + bias[n];
                if (MODE == 0) {
                    v = 0.5f * v * (1.0f + erff(v * 0.70710678118654752f));
                    outb[(size_t)m * N + n] = f2bf(v);
                } else if (MODE == 1) {
                    v = tanhf(v);
                    outb[(size_t)m * N + n] = f2bf(v);
                } else if (MODE == 2) {
                    float tg  = 1.0f / (1.0f + expf(-gate[n]));
                    float tor = torsion[n];
                    float sig = meansig[(size_t)(m >> 9) * 512 + n] * 0.3f;
                    size_t off = (size_t)m * N + n;
                    xio[off] = xio[off] + 0.5f * (v * (1.0f + tg * tor) + sig * tg);
                } else {
                    xio[(size_t)m * N + n] = v;
                }
            }
        }
    }
}

// LayerNorm one row (D=512) per 64-thread block -> bf16 out
__global__ __launch_bounds__(64)
void ln_kernel(const float* __restrict__ x, __hip_bfloat16* __restrict__ out,
               const float* __restrict__ g_base,
               const float* __restrict__ bb_base,
               const int* __restrict__ idx_ptr)
{
    int row = blockIdx.x, lane = threadIdx.x;
    const float* xr = x + (size_t)row * 512;
    float4 v0 = *(const float4*)(xr + lane * 8);
    float4 v1 = *(const float4*)(xr + lane * 8 + 4);
    float vals[8] = {v0.x, v0.y, v0.z, v0.w, v1.x, v1.y, v1.z, v1.w};
    float s = 0.f, s2 = 0.f;
#pragma unroll
    for (int t = 0; t < 8; t++) { s += vals[t]; s2 += vals[t] * vals[t]; }
#pragma unroll
    for (int o = 32; o; o >>= 1) { s += __shfl_xor(s, o); s2 += __shfl_xor(s2, o); }
    float mu  = s * (1.f / 512.f);
    float var = s2 * (1.f / 512.f) - mu * mu;
    float rs  = rsqrtf(var + 1e-5f);
    int idx = idx_ptr[0];
    const float* g  = g_base + (size_t)idx * 512;
    const float* bb = bb_base + (size_t)idx * 512;
    int d0 = lane * 8;
    __align__(16) __hip_bfloat16 o8[8];
#pragma unroll
    for (int t = 0; t < 8; t++)
        o8[t] = f2bf((vals[t] - mu) * rs * g[d0 + t] + bb[d0 + t]);
    *(uint4*)(out + (size_t)row * 512 + d0) = *(const uint4*)o8;
}

__global__ void zero_kernel(float* p, int n)
{
    int i = blockIdx.x * blockDim.x + threadIdx.x;
    if (i < n) p[i] = 0.f;
}

// column means over S: blocks 0..127 -> c (16 b x 8 chunks), 128..255 -> b
__global__ __launch_bounds__(512)
void mean_kernel(const float* __restrict__ xc, const float* __restrict__ xb,
                 float* __restrict__ mc, float* __restrict__ mb)
{
    int bid = blockIdx.x;
    int half = bid >> 7;
    const float* x = half ? xb : xc;
    float* m = half ? mb : mc;
    int b = (bid & 127) >> 3, ch = bid & 7;
    int d = threadIdx.x;
    const float* p = x + ((size_t)b * 512 + ch * 64) * 512 + d;
    float s = 0.f;
#pragma unroll 8
    for (int i = 0; i < 64; i++) s += p[(size_t)i * 512];
    atomicAdd(&m[b * 512 + d], s * (1.f / 512.f));
}

// routing: threads 0..63 -> cortical, 64..127 -> brainstem; top-2 of 8 scores
__global__ __launch_bounds__(128)
void route_kernel(const float* __restrict__ mc, const float* __restrict__ mb,
                  const float* __restrict__ wsel_c, const float* __restrict__ bsel_c,
                  const float* __restrict__ wsel_b, const float* __restrict__ bsel_b,
                  int* __restrict__ idx_out)
{
    int g = threadIdx.x >> 6, lane = threadIdx.x & 63;
    const float* mrow = g ? mb : mc;                 // batch 0 row
    const float* ws = g ? wsel_b : wsel_c;
    const float* bs = g ? bsel_b : bsel_c;
    float acc[8] = {0.f, 0.f, 0.f, 0.f, 0.f, 0.f, 0.f, 0.f};
    for (int d = lane; d < 512; d += 64) {
        float mv = mrow[d];
#pragma unroll
        for (int n = 0; n < 8; n++) acc[n] += mv * ws[d * 8 + n];
    }
#pragma unroll
    for (int o = 32; o; o >>= 1)
#pragma unroll
        for (int n = 0; n < 8; n++) acc[n] += __shfl_xor(acc[n], o);
    if (lane == 0) {
        float adj[8];
#pragma unroll
        for (int n = 0; n < 8; n++) {
            float sc = 1.0f / (1.0f + expf(-(acc[n] + bs[n])));
            adj[n] = 0.7f * sc + 0.15f;
        }
        int i0 = 0;
        for (int n = 1; n < 8; n++) if (adj[n] > adj[i0]) i0 = n;
        int i1 = -1;
        for (int n = 0; n < 8; n++) {
            if (n == i0) continue;
            if (i1 < 0 || adj[n] > adj[i1]) i1 = n;
        }
        idx_out[g * 2 + 0] = i0;
        idx_out[g * 2 + 1] = i1;
    }
}

// transpose two fp32 matrices (src[R][C] -> bf16 dst[C][R]) for block idx_ptr selects
__global__ __launch_bounds__(256)
void transpose2_kernel(const float* __restrict__ w1_base, __hip_bfloat16* __restrict__ w1t,
                       int R1, int C1,
                       const float* __restrict__ w2_base, __hip_bfloat16* __restrict__ w2t,
                       int R2, int C2,
                       const int* __restrict__ idx_ptr)
{
    __shared__ u16 tile[32][33];
    int idx = idx_ptr ? idx_ptr[0] : 0;
    int t1 = (R1 >> 5) * (C1 >> 5);
    int bid = blockIdx.x;
    const float* src; u16* dst; int R, C, tr, tc;
    if (bid < t1) {
        src = w1_base + (size_t)idx * R1 * C1;
        dst = (u16*)w1t; R = R1; C = C1;
        tr = bid / (C1 >> 5); tc = bid % (C1 >> 5);
    } else {
        bid -= t1;
        src = w2_base + (size_t)idx * R2 * C2;
        dst = (u16*)w2t; R = R2; C = C2;
        tr = bid / (C2 >> 5); tc = bid % (C2 >> 5);
    }
    int tx = threadIdx.x & 31, ty = threadIdx.x >> 5;  // 32 x 8
#pragma unroll
    for (int r = ty; r < 32; r += 8) {
        __hip_bfloat16 b = f2bf(src[(size_t)(tr * 32 + r) * C + tc * 32 + tx]);
        tile[r][tx] = *(u16*)&b;
    }
    __syncthreads();
#pragma unroll
    for (int r = ty; r < 32; r += 8)
        dst[(size_t)(tc * 32 + r) * R + tr * 32 + tx] = tile[tx][r];
}

// f32 -> bf16, two tensors (blockIdx.y picks tensor), 8 elems/thread
__global__ __launch_bounds__(256)
void f2b_kernel(const float* __restrict__ xa, const float* __restrict__ xb,
                __hip_bfloat16* __restrict__ oa, __hip_bfloat16* __restrict__ ob)
{
    int i = (blockIdx.x * 256 + threadIdx.x) * 8;
    const float* src = blockIdx.y ? xb : xa;
    __hip_bfloat16* dst = blockIdx.y ? ob : oa;
    float4 f0 = *(const float4*)(src + i);
    float4 f1 = *(const float4*)(src + i + 4);
    __align__(16) __hip_bfloat16 o8[8] = {
        f2bf(f0.x), f2bf(f0.y), f2bf(f0.z), f2bf(f0.w),
        f2bf(f1.x), f2bf(f1.y), f2bf(f1.z), f2bf(f1.w)};
    *(uint4*)(dst + i) = *(const uint4*)o8;
}

extern "C" void kernel_launch(void* const* d_in, const int* in_sizes, int n_in,
                              void* d_out, int out_size, void* d_ws, size_t ws_size,
                              hipStream_t stream)
{
    const float* in_c   = (const float*)d_in[0];
    const float* in_b   = (const float*)d_in[1];
    const float* torsion= (const float*)d_in[2];
    const float* wsel_c = (const float*)d_in[3];
    const float* bsel_c = (const float*)d_in[4];
    const float* wsel_b = (const float*)d_in[5];
    const float* bsel_b = (const float*)d_in[6];
    const float* c_ln_g = (const float*)d_in[7];
    const float* c_ln_b = (const float*)d_in[8];
    const float* c_w1   = (const float*)d_in[9];
    const float* c_b1   = (const float*)d_in[10];
    const float* c_w2   = (const float*)d_in[11];
    const float* c_b2   = (const float*)d_in[12];
    const float* c_gate = (const float*)d_in[13];
    const float* b_ln_g = (const float*)d_in[14];
    const float* b_ln_b = (const float*)d_in[15];
    const float* b_w1   = (const float*)d_in[16];
    const float* b_b1   = (const float*)d_in[17];
    const float* b_w2   = (const float*)d_in[18];
    const float* b_b2   = (const float*)d_in[19];
    const float* b_gate = (const float*)d_in[20];
    const float* w_cross= (const float*)d_in[21];
    const float* b_cross= (const float*)d_in[22];

    const size_t SD = (size_t)8192 * 512;  // 4,194,304 elements per [B,S,D] tensor

    char* w = (char*)d_ws;
    float* x_c    = (float*)w; w += SD * 4;                       // 16.78 MB
    float* x_b    = (float*)w; w += SD * 4;                       // 16.78 MB
    __hip_bfloat16* cbf = (__hip_bfloat16*)w; w += SD * 2;        //  8.39 MB
    __hip_bfloat16* bbf = (__hip_bfloat16*)w; w += SD * 2;        //  8.39 MB
    float* mean_c = (float*)w; w += (size_t)16 * 512 * 4;
    float* mean_b = (float*)w; w += (size_t)16 * 512 * 4;
    int*   idxbuf = (int*)w;   w += 256;
    __hip_bfloat16* w1t = (__hip_bfloat16*)w; w += (size_t)1024 * 512 * 2;
    __hip_bfloat16* w2t = (__hip_bfloat16*)w; w += (size_t)1024 * 512 * 2;
    __hip_bfloat16* wxT = (__hip_bfloat16*)w; w += (size_t)1024 * 512 * 2;

    float* out_c = (float*)d_out;
    float* out_b = out_c + SD;
    float* out_f = out_b + SD;
    // scratch overlays inside d_out (rewritten with real outputs at the end):
    __hip_bfloat16* act_buf = (__hip_bfloat16*)d_out;        // 16 MB (fits in out_c's 16.78 MB)
    __hip_bfloat16* ln_buf  = (__hip_bfloat16*)out_b;        //  8 MB (fits in out_b's 16.78 MB)

    // inputs -> fp32 working state
    hipMemcpyAsync(x_c, in_c, SD * 4, hipMemcpyDeviceToDevice, stream);
    hipMemcpyAsync(x_b, in_b, SD * 4, hipMemcpyDeviceToDevice, stream);
    // w_cross[3] transpose (only last layer's fused output is returned)
    transpose2_kernel<<<512, 256, 0, stream>>>(w_cross + (size_t)3 * 1024 * 512, wxT, 1024, 512,
                                               w_cross, wxT, 32, 32, nullptr);

    for (int l = 0; l < 4; l++) {
        zero_kernel<<<64, 256, 0, stream>>>(mean_c, 16384);  // mean_c+mean_b contiguous
        mean_kernel<<<256, 512, 0, stream>>>(x_c, x_b, mean_c, mean_b);
        route_kernel<<<1, 128, 0, stream>>>(mean_c, mean_b,
            wsel_c + (size_t)l * 512 * 8, bsel_c + (size_t)l * 8,
            wsel_b + (size_t)l * 512 * 8, bsel_b + (size_t)l * 8, idxbuf);

        // cortical pathway: D -> 2D -> D, gelu
        for (int j = 0; j < 2; j++) {
            const int* ip = idxbuf + j;
            transpose2_kernel<<<1024, 256, 0, stream>>>(
                c_w1 + (size_t)l * NB_ * 512 * 1024, w1t, 512, 1024,
                c_w2 + (size_t)l * NB_ * 1024 * 512, w2t, 1024, 512, ip);
            ln_kernel<<<8192, 64, 0, stream>>>(x_c, ln_buf,
                c_ln_g + (size_t)l * NB_ * 512, c_ln_b + (size_t)l * NB_ * 512, ip);
            gemm_mfma<0><<<dim3(64, 8), 256, 0, stream>>>(
                ln_buf, 512, ln_buf, 512, 1 << 30, w1t,
                c_b1 + (size_t)l * NB_ * 1024, 1024, ip,
                8192, 1024, 512, act_buf, nullptr, nullptr, 0, nullptr, nullptr);
            gemm_mfma<2><<<dim3(64, 4), 256, 0, stream>>>(
                act_buf, 1024, act_buf, 1024, 1 << 30, w2t,
                c_b2 + (size_t)l * NB_ * 512, 512, ip,
                8192, 512, 1024, nullptr, x_c,
                c_gate + (size_t)l * NB_ * 512, 512, torsion, mean_b);
        }
        // brainstem pathway: D -> D -> D, tanh
        for (int j = 0; j < 2; j++) {
            const int* ip = idxbuf + 2 + j;
            transpose2_kernel<<<512, 256, 0, stream>>>(
                b_w1 + (size_t)l * NB_ * 512 * 512, w1t, 512, 512,
                b_w2 + (size_t)l * NB_ * 512 * 512, w2t, 512, 512, ip);
            ln_kernel<<<8192, 64, 0, stream>>>(x_b, ln_buf,
                b_ln_g + (size_t)l * NB_ * 512, b_ln_b + (size_t)l * NB_ * 512, ip);
            gemm_mfma<1><<<dim3(64, 4), 256, 0, stream>>>(
                ln_buf, 512, ln_buf, 512, 1 << 30, w1t,
                b_b1 + (size_t)l * NB_ * 512, 512, ip,
                8192, 512, 512, act_buf, nullptr, nullptr, 0, nullptr, nullptr);
            gemm_mfma<2><<<dim3(64, 4), 256, 0, stream>>>(
                act_buf, 512, act_buf, 512, 1 << 30, w2t,
                b_b2 + (size_t)l * NB_ * 512, 512, ip,
                8192, 512, 512, nullptr, x_b,
                b_gate + (size_t)l * NB_ * 512, 512, torsion, mean_c);
        }
    }

    // final bf16 copies of c/b for the fused GEMM's A operand
    f2b_kernel<<<dim3(2048, 2), 256, 0, stream>>>(x_c, x_b, cbf, bbf);
    // fp32 outputs c, b (overwrites the scratch overlays in d_out)
    hipMemcpyAsync(out_c, x_c, SD * 4, hipMemcpyDeviceToDevice, stream);
    hipMemcpyAsync(out_b, x_b, SD * 4, hipMemcpyDeviceToDevice, stream);
    // fused = concat([c,b]) @ w_cross[3] + b_cross[3]  (fp32 out)
    gemm_mfma<3><<<dim3(64, 4), 256, 0, stream>>>(
        cbf, 512, bbf, 512, 512, wxT,
        b_cross + (size_t)3 * 512, 0, nullptr,
        8192, 512, 1024, nullptr, out_f, nullptr, 0, nullptr, nullptr);
}